// Round 1
// baseline (233.987 us; speedup 1.0000x reference)
//
#include <hip/hip_runtime.h>

#define KC   32              // clusters
#define CH   16              // channels
#define NB   8               // batch
#define NPI  (512*512)       // pixels per image
#define BPI  64              // blocks per image for heavy kernels
#define TPB  256
#define PPB  (NPI/BPI)       // 4096 pixels per block
#define ITERS (PPB/TPB)      // 16

// ws layout (floats):
#define WS_CNT 0                 // counts [B][K]            : 256
#define WS_SUM 256               // sums   [B][K][C]         : 4096
#define WS_CEN 4352              // centroids [B][C][K]      : 4096
#define WS_PR  8448              // push + 1e-4*reg per image: 8
#define WS_PL  8456              // pull d^2 sums per image  : 8
#define WS_TOT 8464

__global__ void zero_ws_kernel(float* __restrict__ ws) {
    int i = blockIdx.x * 256 + threadIdx.x;
    if (i < WS_TOT) ws[i] = 0.f;
}

__global__ __launch_bounds__(TPB) void segsum_kernel(
    const float4* __restrict__ embv, const int* __restrict__ lab,
    float* __restrict__ ws) {
    __shared__ float lsum[CH * KC];   // [c][k]: LDS bank == k -> no bank conflicts
    __shared__ float lcnt[KC];
    const int t = threadIdx.x;
    for (int i = t; i < CH * KC; i += TPB) lsum[i] = 0.f;
    if (t < KC) lcnt[t] = 0.f;
    __syncthreads();

    const int b   = blockIdx.x / BPI;
    const int blk = blockIdx.x % BPI;
    const size_t pix0 = (size_t)b * NPI + (size_t)blk * PPB;

    for (int it = 0; it < ITERS; ++it) {
        const size_t p = pix0 + (size_t)it * TPB + t;
        const int L = lab[p];
        atomicAdd(&lcnt[L], 1.f);
        const float4 v0 = embv[p * 4 + 0];
        const float4 v1 = embv[p * 4 + 1];
        const float4 v2 = embv[p * 4 + 2];
        const float4 v3 = embv[p * 4 + 3];
        atomicAdd(&lsum[ 0 * KC + L], v0.x);
        atomicAdd(&lsum[ 1 * KC + L], v0.y);
        atomicAdd(&lsum[ 2 * KC + L], v0.z);
        atomicAdd(&lsum[ 3 * KC + L], v0.w);
        atomicAdd(&lsum[ 4 * KC + L], v1.x);
        atomicAdd(&lsum[ 5 * KC + L], v1.y);
        atomicAdd(&lsum[ 6 * KC + L], v1.z);
        atomicAdd(&lsum[ 7 * KC + L], v1.w);
        atomicAdd(&lsum[ 8 * KC + L], v2.x);
        atomicAdd(&lsum[ 9 * KC + L], v2.y);
        atomicAdd(&lsum[10 * KC + L], v2.z);
        atomicAdd(&lsum[11 * KC + L], v2.w);
        atomicAdd(&lsum[12 * KC + L], v3.x);
        atomicAdd(&lsum[13 * KC + L], v3.y);
        atomicAdd(&lsum[14 * KC + L], v3.z);
        atomicAdd(&lsum[15 * KC + L], v3.w);
    }
    __syncthreads();

    float* gsum = ws + WS_SUM + (size_t)b * KC * CH;   // [K][C]
    for (int i = t; i < CH * KC; i += TPB) {
        const int c = i >> 5, k = i & 31;
        atomicAdd(&gsum[k * CH + c], lsum[i]);
    }
    if (t < KC) atomicAdd(ws + WS_CNT + b * KC + t, lcnt[t]);
}

__global__ __launch_bounds__(512) void centroid_push_kernel(float* __restrict__ ws) {
    __shared__ float cent[CH * KC];   // [c][k]
    __shared__ float validf[KC];
    __shared__ float red[8];
    const int b = blockIdx.x, t = threadIdx.x;
    const float* gcnt = ws + WS_CNT + b * KC;
    const float* gsum = ws + WS_SUM + (size_t)b * KC * CH;

    if (t < KC) validf[t] = (gcnt[t] > 0.f) ? 1.f : 0.f;

    const int k = t & 31, c = t >> 5;            // t in [0,512)
    const float cnt = gcnt[k];
    const float ce  = (cnt > 0.f) ? gsum[k * CH + c] / cnt : 0.f;
    cent[c * KC + k] = ce;
    ws[WS_CEN + (size_t)b * CH * KC + c * KC + k] = ce;
    const float regacc = ce * ce;                // invalid clusters contribute 0
    __syncthreads();

    // pairwise push: p = i*32+j, strictly upper triangle
    float pushacc = 0.f;
    for (int p = t; p < KC * KC; p += 512) {
        const int i = p >> 5, j = p & 31;
        if (i < j && validf[i] > 0.f && validf[j] > 0.f) {
            float pd = 0.f;
            #pragma unroll
            for (int cc = 0; cc < CH; ++cc)
                pd += fabsf(cent[cc * KC + i] - cent[cc * KC + j]);
            const float h = 0.25f - pd;
            if (h > 0.f) pushacc += h * h;
        }
    }

    float v = pushacc;
    #pragma unroll
    for (int off = 32; off; off >>= 1) v += __shfl_down(v, off, 64);
    if ((t & 63) == 0) red[t >> 6] = v;
    __syncthreads();
    float pushsum = 0.f;
    if (t == 0) { for (int i = 0; i < 8; ++i) pushsum += red[i]; }
    __syncthreads();

    v = regacc;
    #pragma unroll
    for (int off = 32; off; off >>= 1) v += __shfl_down(v, off, 64);
    if ((t & 63) == 0) red[t >> 6] = v;
    __syncthreads();

    if (t == 0) {
        float regsum = 0.f;
        for (int i = 0; i < 8; ++i) regsum += red[i];
        float nv = 0.f;
        for (int i = 0; i < KC; ++i) nv += validf[i];
        const float ncomp = nv * (nv - 1.f) * 0.5f;
        const float push  = (nv >= 2.f) ? pushsum / fmaxf(ncomp, 1.f) : 0.f;
        const float reg   = regsum / fmaxf(nv * (float)CH, 1.f);
        ws[WS_PR + b] = push + 1e-4f * reg;
    }
}

__global__ __launch_bounds__(TPB) void pull_kernel(
    const float4* __restrict__ embv, const int* __restrict__ lab,
    float* __restrict__ ws) {
    __shared__ float cent[CH * KC];   // [c][k]: read bank == label -> broadcast or spread
    __shared__ float red[4];
    const int t = threadIdx.x;
    const int b = blockIdx.x / BPI, blk = blockIdx.x % BPI;
    for (int i = t; i < CH * KC; i += TPB)
        cent[i] = ws[WS_CEN + (size_t)b * CH * KC + i];
    __syncthreads();

    float acc = 0.f;
    const size_t pix0 = (size_t)b * NPI + (size_t)blk * PPB;
    for (int it = 0; it < ITERS; ++it) {
        const size_t p = pix0 + (size_t)it * TPB + t;
        const int L = lab[p];
        const float4 v0 = embv[p * 4 + 0];
        const float4 v1 = embv[p * 4 + 1];
        const float4 v2 = embv[p * 4 + 2];
        const float4 v3 = embv[p * 4 + 3];
        float d = 0.f;
        d += fabsf(v0.x - cent[ 0 * KC + L]);
        d += fabsf(v0.y - cent[ 1 * KC + L]);
        d += fabsf(v0.z - cent[ 2 * KC + L]);
        d += fabsf(v0.w - cent[ 3 * KC + L]);
        d += fabsf(v1.x - cent[ 4 * KC + L]);
        d += fabsf(v1.y - cent[ 5 * KC + L]);
        d += fabsf(v1.z - cent[ 6 * KC + L]);
        d += fabsf(v1.w - cent[ 7 * KC + L]);
        d += fabsf(v2.x - cent[ 8 * KC + L]);
        d += fabsf(v2.y - cent[ 9 * KC + L]);
        d += fabsf(v2.z - cent[10 * KC + L]);
        d += fabsf(v2.w - cent[11 * KC + L]);
        d += fabsf(v3.x - cent[12 * KC + L]);
        d += fabsf(v3.y - cent[13 * KC + L]);
        d += fabsf(v3.z - cent[14 * KC + L]);
        d += fabsf(v3.w - cent[15 * KC + L]);
        acc += d * d;
    }
    #pragma unroll
    for (int off = 32; off; off >>= 1) acc += __shfl_down(acc, off, 64);
    if ((t & 63) == 0) red[t >> 6] = acc;
    __syncthreads();
    if (t == 0) atomicAdd(ws + WS_PL + b, red[0] + red[1] + red[2] + red[3]);
}

__global__ void final_kernel(const float* __restrict__ ws, float* __restrict__ out) {
    const int t = threadIdx.x;
    float v = 0.f;
    if (t < NB) v = ws[WS_PR + t] + ws[WS_PL + t] * (1.f / (float)NPI);
    #pragma unroll
    for (int off = 32; off; off >>= 1) v += __shfl_down(v, off, 64);
    if (t == 0) out[0] = v * (1.f / (float)NB);
}

extern "C" void kernel_launch(void* const* d_in, const int* in_sizes, int n_in,
                              void* d_out, int out_size, void* d_ws, size_t ws_size,
                              hipStream_t stream) {
    const float4* emb = (const float4*)d_in[0];
    const int*    lab = (const int*)d_in[1];
    float* ws  = (float*)d_ws;
    float* out = (float*)d_out;

    hipLaunchKernelGGL(zero_ws_kernel, dim3((WS_TOT + 255) / 256), dim3(256), 0, stream, ws);
    hipLaunchKernelGGL(segsum_kernel, dim3(NB * BPI), dim3(TPB), 0, stream, emb, lab, ws);
    hipLaunchKernelGGL(centroid_push_kernel, dim3(NB), dim3(512), 0, stream, ws);
    hipLaunchKernelGGL(pull_kernel, dim3(NB * BPI), dim3(TPB), 0, stream, emb, lab, ws);
    hipLaunchKernelGGL(final_kernel, dim3(1), dim3(64), 0, stream, ws, out);
}

// Round 2
// 74.049 us; speedup vs baseline: 3.1599x; 3.1599x over previous
//
#include <hip/hip_runtime.h>

#define KC 32
#define CH 16
#define NB 8
#define NPI (512*512)

// segsum decomposition
#define SBPI 128              // blocks per image
#define SPPB (NPI/SBPI)       // 2048 px per block
#define SPW  (SPPB/4)         // 512 px per wave
#define SCH  (SPW/64)         // 8 chunks of 64 px

// pull decomposition
#define PBPI 128
#define PPPB (NPI/PBPI)       // 2048
#define PIT  (PPPB/256)       // 8

// ws layout (floats)
#define WS_CNT 0                         // [8][32]
#define WS_SUM (WS_CNT + NB*KC)          // [8][32][16]
#define WS_CEN (WS_SUM + NB*KC*CH)       // [8][16][32]
#define WS_PR  (WS_CEN + NB*CH*KC)       // [8]
#define WS_PLP (WS_PR + NB)              // [8*PBPI] pull partials (overwritten, no zero needed)
#define WS_TOT (WS_PLP + NB*PBPI)
#define WS_NZERO (NB*KC + NB*KC*CH)      // only CNT+SUM are accumulated -> zeroed

typedef float f32x16 __attribute__((ext_vector_type(16)));
typedef short short8 __attribute__((ext_vector_type(8)));

__device__ __forceinline__ unsigned short f2bf(float x) {
  unsigned u = __builtin_bit_cast(unsigned, x);
  u += 0x7FFFu + ((u >> 16) & 1u);          // RNE truncate to bf16
  return (unsigned short)(u >> 16);
}
__device__ __forceinline__ unsigned packbf(float lo, float hi) {
  return (unsigned)f2bf(lo) | ((unsigned)f2bf(hi) << 16);
}

__global__ void zero_ws_kernel(float* __restrict__ ws) {
  int i = blockIdx.x * 256 + threadIdx.x;
  if (i < WS_NZERO) ws[i] = 0.f;
}

// sums[k][c] + counts[k] via onehot^T * emb, one 32x32x16 bf16 MFMA per 16 pixels.
// A[32 labels x 16 px] = onehot, B[16 px x 32 cols] = {ch0..ch15, ones, 0...}.
// Per-wave private LDS staging (in-order DS => no barriers in hot loop).
__global__ __launch_bounds__(256) void segsum_kernel(
    const float4* __restrict__ embv, const int* __restrict__ lab,
    float* __restrict__ ws) {
  __shared__ unsigned smem[4][8][68];   // [wave][ch-pair][px + pad] bf16x2, stride 68 dwords
  __shared__ int      slab[4][64];
  __shared__ float    sred[4][KC * 17];

  const int t = threadIdx.x, w = t >> 6, l = t & 63;
  const int b = blockIdx.x / SBPI, blk = blockIdx.x % SBPI;
  const size_t base = (size_t)b * NPI + (size_t)blk * SPPB + (size_t)w * SPW;
  const int h = l >> 5;     // k-half of the MFMA operands
  const int m = l & 31;     // A row (label) / B col (channel|count)

  f32x16 acc;
  #pragma unroll
  for (int i = 0; i < 16; ++i) acc[i] = 0.f;

  float4 c0, c1, c2, c3; int cl;
  {
    const float4* ep = embv + (base + l) * 4;
    c0 = ep[0]; c1 = ep[1]; c2 = ep[2]; c3 = ep[3];
    cl = lab[base + l];
  }

  for (int ch = 0; ch < SCH; ++ch) {
    // stage current chunk: transposed, bf16-packed channel pairs
    smem[w][0][l] = packbf(c0.x, c0.y);
    smem[w][1][l] = packbf(c0.z, c0.w);
    smem[w][2][l] = packbf(c1.x, c1.y);
    smem[w][3][l] = packbf(c1.z, c1.w);
    smem[w][4][l] = packbf(c2.x, c2.y);
    smem[w][5][l] = packbf(c2.z, c2.w);
    smem[w][6][l] = packbf(c3.x, c3.y);
    smem[w][7][l] = packbf(c3.z, c3.w);
    slab[w][l] = cl;

    // prefetch next chunk (hides HBM latency under MFMA steps)
    if (ch + 1 < SCH) {
      const size_t p = base + (size_t)(ch + 1) * 64 + l;
      const float4* ep = embv + p * 4;
      c0 = ep[0]; c1 = ep[1]; c2 = ep[2]; c3 = ep[3];
      cl = lab[p];
    }

    #pragma unroll
    for (int s = 0; s < 4; ++s) {
      const int4* lp = (const int4*)&slab[w][s * 16 + 8 * h];
      const int4 la = lp[0], lb = lp[1];
      const short ONE = (short)0x3F80;  // bf16 1.0
      short8 av;
      av[0] = (la.x == m) ? ONE : (short)0; av[1] = (la.y == m) ? ONE : (short)0;
      av[2] = (la.z == m) ? ONE : (short)0; av[3] = (la.w == m) ? ONE : (short)0;
      av[4] = (lb.x == m) ? ONE : (short)0; av[5] = (lb.y == m) ? ONE : (short)0;
      av[6] = (lb.z == m) ? ONE : (short)0; av[7] = (lb.w == m) ? ONE : (short)0;

      short8 bv;
      if (m < CH) {
        const uint4* fp = (const uint4*)&smem[w][m >> 1][s * 16 + 8 * h];
        const uint4 u0 = fp[0], u1 = fp[1];
        const unsigned sh = (unsigned)(m & 1) * 16u;
        bv[0] = (short)((u0.x >> sh) & 0xFFFFu); bv[1] = (short)((u0.y >> sh) & 0xFFFFu);
        bv[2] = (short)((u0.z >> sh) & 0xFFFFu); bv[3] = (short)((u0.w >> sh) & 0xFFFFu);
        bv[4] = (short)((u1.x >> sh) & 0xFFFFu); bv[5] = (short)((u1.y >> sh) & 0xFFFFu);
        bv[6] = (short)((u1.z >> sh) & 0xFFFFu); bv[7] = (short)((u1.w >> sh) & 0xFFFFu);
      } else {
        const short cv = (m == CH) ? ONE : (short)0;   // col 16 = ones -> counts
        #pragma unroll
        for (int e = 0; e < 8; ++e) bv[e] = cv;
      }
      acc = __builtin_amdgcn_mfma_f32_32x32x16_bf16(av, bv, acc, 0, 0, 0);
    }
  }

  // block-level reduce of the 4 waves' [32 x 17] partials, then one atomic per cell
  if (m < 17) {
    #pragma unroll
    for (int r = 0; r < 16; ++r) {
      const int row = (r & 3) + 8 * (r >> 2) + 4 * h;   // verified C/D layout (m74/m101)
      sred[w][row * 17 + m] = acc[r];
    }
  }
  __syncthreads();
  for (int i = t; i < KC * 17; i += 256) {
    const float v = sred[0][i] + sred[1][i] + sred[2][i] + sred[3][i];
    const int row = i / 17, c = i - row * 17;
    float* dst = (c < CH) ? &ws[WS_SUM + (b * KC + row) * CH + c]
                          : &ws[WS_CNT + b * KC + row];
    __hip_atomic_fetch_add(dst, v, __ATOMIC_RELAXED, __HIP_MEMORY_SCOPE_AGENT);
  }
}

__global__ __launch_bounds__(512) void centroid_push_kernel(float* __restrict__ ws) {
  __shared__ float cent[CH * KC];   // [c][k]
  __shared__ float validf[KC];
  __shared__ float red[8];
  const int b = blockIdx.x, t = threadIdx.x;
  const float* gcnt = ws + WS_CNT + b * KC;
  const float* gsum = ws + WS_SUM + (size_t)b * KC * CH;

  if (t < KC) validf[t] = (gcnt[t] > 0.f) ? 1.f : 0.f;

  const int k = t & 31, c = t >> 5;
  const float cnt = gcnt[k];
  const float ce  = (cnt > 0.f) ? gsum[k * CH + c] / cnt : 0.f;
  cent[c * KC + k] = ce;
  ws[WS_CEN + (size_t)b * CH * KC + c * KC + k] = ce;
  const float regacc = ce * ce;
  __syncthreads();

  float pushacc = 0.f;
  for (int p = t; p < KC * KC; p += 512) {
    const int i = p >> 5, j = p & 31;
    if (i < j && validf[i] > 0.f && validf[j] > 0.f) {
      float pd = 0.f;
      #pragma unroll
      for (int cc = 0; cc < CH; ++cc)
        pd += fabsf(cent[cc * KC + i] - cent[cc * KC + j]);
      const float hi = 0.25f - pd;
      if (hi > 0.f) pushacc += hi * hi;
    }
  }

  float v = pushacc;
  #pragma unroll
  for (int off = 32; off; off >>= 1) v += __shfl_down(v, off, 64);
  if ((t & 63) == 0) red[t >> 6] = v;
  __syncthreads();
  float pushsum = 0.f;
  if (t == 0) { for (int i = 0; i < 8; ++i) pushsum += red[i]; }
  __syncthreads();

  v = regacc;
  #pragma unroll
  for (int off = 32; off; off >>= 1) v += __shfl_down(v, off, 64);
  if ((t & 63) == 0) red[t >> 6] = v;
  __syncthreads();

  if (t == 0) {
    float regsum = 0.f;
    for (int i = 0; i < 8; ++i) regsum += red[i];
    float nv = 0.f;
    for (int i = 0; i < KC; ++i) nv += validf[i];
    const float ncomp = nv * (nv - 1.f) * 0.5f;
    const float push  = (nv >= 2.f) ? pushsum / fmaxf(ncomp, 1.f) : 0.f;
    const float reg   = regsum / fmaxf(nv * (float)CH, 1.f);
    ws[WS_PR + b] = push + 1e-4f * reg;
  }
}

__global__ __launch_bounds__(256) void pull_kernel(
    const float4* __restrict__ embv, const int* __restrict__ lab,
    float* __restrict__ ws) {
  __shared__ float cent[CH * KC];   // [c][k]
  __shared__ float red[4];
  const int t = threadIdx.x;
  const int b = blockIdx.x / PBPI, blk = blockIdx.x % PBPI;
  for (int i = t; i < CH * KC; i += 256)
    cent[i] = ws[WS_CEN + (size_t)b * CH * KC + i];
  __syncthreads();

  float acc = 0.f;
  const size_t pix0 = (size_t)b * NPI + (size_t)blk * PPPB;
  for (int it = 0; it < PIT; ++it) {
    const size_t p = pix0 + (size_t)it * 256 + t;
    const int L = lab[p];
    const float4 v0 = embv[p * 4 + 0];
    const float4 v1 = embv[p * 4 + 1];
    const float4 v2 = embv[p * 4 + 2];
    const float4 v3 = embv[p * 4 + 3];
    float d = 0.f;
    d += fabsf(v0.x - cent[ 0 * KC + L]);
    d += fabsf(v0.y - cent[ 1 * KC + L]);
    d += fabsf(v0.z - cent[ 2 * KC + L]);
    d += fabsf(v0.w - cent[ 3 * KC + L]);
    d += fabsf(v1.x - cent[ 4 * KC + L]);
    d += fabsf(v1.y - cent[ 5 * KC + L]);
    d += fabsf(v1.z - cent[ 6 * KC + L]);
    d += fabsf(v1.w - cent[ 7 * KC + L]);
    d += fabsf(v2.x - cent[ 8 * KC + L]);
    d += fabsf(v2.y - cent[ 9 * KC + L]);
    d += fabsf(v2.z - cent[10 * KC + L]);
    d += fabsf(v2.w - cent[11 * KC + L]);
    d += fabsf(v3.x - cent[12 * KC + L]);
    d += fabsf(v3.y - cent[13 * KC + L]);
    d += fabsf(v3.z - cent[14 * KC + L]);
    d += fabsf(v3.w - cent[15 * KC + L]);
    acc += d * d;
  }
  #pragma unroll
  for (int off = 32; off; off >>= 1) acc += __shfl_down(acc, off, 64);
  if ((t & 63) == 0) red[t >> 6] = acc;
  __syncthreads();
  if (t == 0) ws[WS_PLP + blockIdx.x] = red[0] + red[1] + red[2] + red[3];
}

__global__ void final_kernel(const float* __restrict__ ws, float* __restrict__ out) {
  __shared__ float simg[NB];
  const int t = threadIdx.x;            // 256 threads
  const int img = t >> 5, j = t & 31;   // 32 threads per image
  float v = 0.f;
  #pragma unroll
  for (int q = 0; q < PBPI / 32; ++q)
    v += ws[WS_PLP + img * PBPI + j + 32 * q];
  #pragma unroll
  for (int off = 16; off; off >>= 1) v += __shfl_down(v, off, 32);
  if (j == 0) simg[img] = v;
  __syncthreads();
  if (t == 0) {
    float s = 0.f;
    for (int b2 = 0; b2 < NB; ++b2)
      s += ws[WS_PR + b2] + simg[b2] * (1.f / (float)NPI);
    out[0] = s * (1.f / (float)NB);
  }
}

extern "C" void kernel_launch(void* const* d_in, const int* in_sizes, int n_in,
                              void* d_out, int out_size, void* d_ws, size_t ws_size,
                              hipStream_t stream) {
  const float4* emb = (const float4*)d_in[0];
  const int*    lab = (const int*)d_in[1];
  float* ws  = (float*)d_ws;
  float* out = (float*)d_out;

  hipLaunchKernelGGL(zero_ws_kernel, dim3((WS_NZERO + 255) / 256), dim3(256), 0, stream, ws);
  hipLaunchKernelGGL(segsum_kernel, dim3(NB * SBPI), dim3(256), 0, stream, emb, lab, ws);
  hipLaunchKernelGGL(centroid_push_kernel, dim3(NB), dim3(512), 0, stream, ws);
  hipLaunchKernelGGL(pull_kernel, dim3(NB * PBPI), dim3(256), 0, stream, emb, lab, ws);
  hipLaunchKernelGGL(final_kernel, dim3(1), dim3(256), 0, stream, ws, out);
}